// Round 13
// baseline (240.975 us; speedup 1.0000x reference)
//
#include <hip/hip_runtime.h>
#include <hip/hip_bf16.h>

#define N_NODES 50000
#define IN_CH 128
#define HID 128
#define OUT_CH 64
#define N_EDGES 800000
#define N_TOT_EDGES (N_EDGES + N_NODES)         // + self loops
#define ET_PAD (N_TOT_EDGES + 3 * N_NODES)      // worst-case pad-to-4 per node

typedef float float4v __attribute__((ext_vector_type(4)));

__device__ __forceinline__ unsigned bf16_rne(float f) {
    unsigned u = __float_as_uint(f);
    return (u + 0x7fffu + ((u >> 16) & 1u)) >> 16;
}

// ---------------- CSR build ----------------

__global__ void k_init(int* cnt, int* cur, float* alsA, float* aldA,
                       float* alsB, float* aldB, int n) {
    int i = blockIdx.x * 256 + threadIdx.x;
    if (i < n) {
        cnt[i] = 1; cur[i] = 0;              // self-loop contributes 1
        alsA[i] = 0.f; aldA[i] = 0.f;        // per-layer attention-dot accumulators
        alsB[i] = 0.f; aldB[i] = 0.f;
    }
}

__global__ void k_count(const int* __restrict__ dst_row, int* __restrict__ cnt, int e) {
    int i = blockIdx.x * 256 + threadIdx.x;
    if (i < e) atomicAdd(&cnt[dst_row[i]], 1);
}

// inclusive scan of PADDED counts -> off[i+1]; per-block sums to bsum.
__global__ void k_scan1(const int* __restrict__ cnt, int* __restrict__ off,
                        int* __restrict__ bsum, int n) {
    __shared__ int s[256];
    int t = threadIdx.x;
    int i = blockIdx.x * 256 + t;
    int v = (i < n) ? ((cnt[i] + 3) & ~3) : 0;
    s[t] = v;
    __syncthreads();
    for (int d = 1; d < 256; d <<= 1) {
        int x = (t >= d) ? s[t - d] : 0;
        __syncthreads();
        s[t] += x;
        __syncthreads();
    }
    if (i < n) off[i + 1] = s[t];
    if (t == 255) bsum[blockIdx.x] = s[255];
}

__global__ void k_scan2(int* __restrict__ bsum, int nb) {  // single block, nb <= 256
    __shared__ int s[256];
    int t = threadIdx.x;
    int v = (t < nb) ? bsum[t] : 0;
    s[t] = v;
    __syncthreads();
    for (int d = 1; d < 256; d <<= 1) {
        int x = (t >= d) ? s[t - d] : 0;
        __syncthreads();
        s[t] += x;
        __syncthreads();
    }
    if (t < nb) bsum[t] = s[t] - v;  // exclusive prefix
}

__global__ void k_scan3(int* __restrict__ off, const int* __restrict__ bsum, int n) {
    int i = blockIdx.x * 256 + threadIdx.x;
    if (i < n) off[i + 1] += bsum[blockIdx.x];
    if (i == 0) off[0] = 0;
}

__global__ void k_fill(const int* __restrict__ ei, const int* __restrict__ off,
                       int* __restrict__ cur, int* __restrict__ csr, int e, int n) {
    int i = blockIdx.x * 256 + threadIdx.x;
    if (i >= e + n) return;
    int src, dst;
    if (i < e) { src = ei[i]; dst = ei[e + i]; }
    else       { src = dst = i - e; }
    int pos = off[dst] + atomicAdd(&cur[dst], 1);
    csr[pos] = src;
}

// ---------------- GEMM (h = X @ W) + fused attention dots ----------------
// W staged in LDS (32KB). X streams via broadcast float4 with an EXPLICIT
// 2-deep software pipeline (r12 post-mortem: compiler kept zero prefetch
// state -> one full memory latency stalled per k-iteration, VALUBusy 40%).
// k-chunk = 8; two alternating register buffers (no runtime indexing); loads
// for chunk k+8 issue before computing chunk k, so their waitcnt lands ~256cy
// later, overlapped with FMAs. Accumulation order per output unchanged.
template<int N, bool BF16OUT>
__global__ __launch_bounds__(256) void gemm_att(
        const float* __restrict__ X, const float* __restrict__ W,
        const float* __restrict__ asrc, const float* __restrict__ adst,
        void* __restrict__ HcV, float* __restrict__ als, float* __restrict__ ald,
        int M) {
    constexpr int K = 128;
    constexpr int CT = N / 64;                 // col tiles (2 or 1)
    __shared__ float Ws[K * 64];               // 32 KB
    const int ct = blockIdx.x % CT;
    const int r0 = (blockIdx.x / CT) * 64;
    const int t  = threadIdx.x;
    const int c  = t & 15;                     // col group (4 cols each)
    const int rg = t >> 4;                     // row group (4 rows each)
    const int col = ct * 64 + c * 4;
    const int c4 = c * 4;

    for (int i = t * 4; i < K * 64; i += 1024) {
        int k = i >> 6, cc = i & 63;
        *(float4*)&Ws[i] = *(const float4*)&W[(size_t)k * N + ct * 64 + cc];
    }
    __syncthreads();

    const float* Xr[4];
    #pragma unroll
    for (int r = 0; r < 4; ++r) {
        int row = r0 + rg * 4 + r; if (row >= M) row = M - 1;
        Xr[r] = X + (size_t)row * K;
    }

    struct XChunk { float v[8]; };
    XChunk xc[4], xn[4];

    #define LOADX(DST, KK)                                              \
        {                                                               \
            _Pragma("unroll")                                           \
            for (int r = 0; r < 4; ++r) {                               \
                float4 t0 = *(const float4*)&Xr[r][(KK)];               \
                float4 t1 = *(const float4*)&Xr[r][(KK) + 4];           \
                DST[r].v[0] = t0.x; DST[r].v[1] = t0.y;                 \
                DST[r].v[2] = t0.z; DST[r].v[3] = t0.w;                 \
                DST[r].v[4] = t1.x; DST[r].v[5] = t1.y;                 \
                DST[r].v[6] = t1.z; DST[r].v[7] = t1.w;                 \
            }                                                           \
        }

    float acc[4][4] = {};
    #define COMPUTE(KK, BUF)                                            \
        {                                                               \
            _Pragma("unroll")                                           \
            for (int u = 0; u < 8; ++u) {                               \
                float4 wv = *(const float4*)&Ws[((KK) + u) * 64 + c4];  \
                _Pragma("unroll")                                       \
                for (int r = 0; r < 4; ++r) {                           \
                    float x = BUF[r].v[u];                              \
                    acc[r][0] += x * wv.x;                              \
                    acc[r][1] += x * wv.y;                              \
                    acc[r][2] += x * wv.z;                              \
                    acc[r][3] += x * wv.w;                              \
                }                                                       \
            }                                                           \
        }

    LOADX(xc, 0)
    int k0 = 0;
    for (; k0 < K - 16; k0 += 16) {            // K=128: 7 iterations
        LOADX(xn, k0 + 8)
        COMPUTE(k0, xc)
        LOADX(xc, k0 + 16)
        COMPUTE(k0 + 8, xn)
    }
    // k0 == 112: two chunks remain (112, 120)
    LOADX(xn, k0 + 8)
    COMPUTE(k0, xc)
    COMPUTE(k0 + 8, xn)
    #undef LOADX
    #undef COMPUTE

    const float as0 = asrc[col], as1 = asrc[col+1], as2 = asrc[col+2], as3 = asrc[col+3];
    const float ad0 = adst[col], ad1 = adst[col+1], ad2 = adst[col+2], ad3 = adst[col+3];
    #pragma unroll
    for (int r = 0; r < 4; ++r) {
        int row = r0 + rg * 4 + r;
        float ps = acc[r][0]*as0 + acc[r][1]*as1 + acc[r][2]*as2 + acc[r][3]*as3;
        float pd = acc[r][0]*ad0 + acc[r][1]*ad1 + acc[r][2]*ad2 + acc[r][3]*ad3;
        #pragma unroll
        for (int mask = 1; mask < 16; mask <<= 1) {   // reduce over 16 col-groups
            ps += __shfl_xor(ps, mask);
            pd += __shfl_xor(pd, mask);
        }
        if (row < M) {
            if (BF16OUT) {
                // bf16 chunk-major: Hb[chunk][row][32], chunk = col>>5
                unsigned short* Hb = (unsigned short*)HcV;
                size_t cstride = (size_t)M * 32;
                unsigned short* Hq = Hb + (size_t)(col >> 5) * cstride
                                   + (size_t)row * 32 + (col & 31);
                uint2 p;
                p.x = bf16_rne(acc[r][0]) | (bf16_rne(acc[r][1]) << 16);
                p.y = bf16_rne(acc[r][2]) | (bf16_rne(acc[r][3]) << 16);
                *(uint2*)Hq = p;
            } else {
                // f32 chunk-major: Hc[chunk][row][16], chunk = col>>4
                float* Hc = (float*)HcV;
                size_t cstride = (size_t)M * 16;
                float* Hq = Hc + (size_t)(col >> 4) * cstride
                          + (size_t)row * 16 + (col & 15);
                *(float4*)Hq = make_float4(acc[r][0], acc[r][1], acc[r][2], acc[r][3]);
            }
            if (c == 0) {
                atomicAdd(&als[row], ps);
                atomicAdd(&ald[row], pd);
            }
        }
    }
}

// ---------------- edge weights: packed u32 = (src<<16) | bf16(exp(leaky(e))) ----
__global__ __launch_bounds__(256) void k_edgew(
        const float* __restrict__ als, const float* __restrict__ ald,
        const int* __restrict__ off, const int* __restrict__ cnt,
        const int* __restrict__ csr,
        unsigned* __restrict__ ew, float* __restrict__ invden, int n) {
    const int fl = threadIdx.x & 15;
    const int v = blockIdx.x * 16 + (threadIdx.x >> 4);
    if (v >= n) return;
    const int start = off[v], end = start + cnt[v];
    const float aldv = ald[v];
    float s = 0.f;
    for (int j = start + fl; j < end; j += 16) {
        int src = __builtin_nontemporal_load(&csr[j]);
        float e = als[src] + aldv;
        e = e > 0.f ? e : 0.2f * e;
        unsigned r = bf16_rne(__expf(e));
        ew[j] = ((unsigned)src << 16) | r;
        s += __uint_as_float(r << 16);
    }
    #pragma unroll
    for (int d = 1; d < 16; d <<= 1) s += __shfl_xor(s, d);
    if (fl == 0) invden[v] = 1.f / (s + 1e-16f);
}

// ---------------- layer-1 SpMM (bf16 H, 32-feature chunks, 4 passes) ------------
__global__ __launch_bounds__(256) void k_spmm_bf16(
        const unsigned short* __restrict__ Hb, const unsigned* __restrict__ ew,
        const float* __restrict__ invden, const float* __restrict__ bias,
        const int* __restrict__ off, float* __restrict__ out, int n) {
    const int chunk = blockIdx.x & 3;             // NCH = 128/32 = 4
    const int v = (blockIdx.x >> 2) * 64 + (threadIdx.x >> 2);
    if (v >= n) return;
    const int q = threadIdx.x & 3;                // 8-feat group 0..3
    const int start = off[v], end = off[v + 1];   // padded: multiple of 4, >= 4
    const unsigned short* __restrict__ Hch = Hb + (size_t)chunk * (size_t)n * 32 + q * 8;

    float a0[8] = {}, a1[8] = {}, a2[8] = {}, a3[8] = {};

    #define GATB(E, A)                                                   \
        {                                                                \
            float w_ = __uint_as_float((E) << 16);                       \
            uint4 h_ = *(const uint4*)&Hch[(size_t)((E) >> 16) * 32];    \
            A[0] += w_ * __uint_as_float(h_.x << 16);                    \
            A[1] += w_ * __uint_as_float(h_.x & 0xffff0000u);            \
            A[2] += w_ * __uint_as_float(h_.y << 16);                    \
            A[3] += w_ * __uint_as_float(h_.y & 0xffff0000u);            \
            A[4] += w_ * __uint_as_float(h_.z << 16);                    \
            A[5] += w_ * __uint_as_float(h_.z & 0xffff0000u);            \
            A[6] += w_ * __uint_as_float(h_.w << 16);                    \
            A[7] += w_ * __uint_as_float(h_.w & 0xffff0000u);            \
        }
    #define GATB4(Q) GATB((Q).x, a0) GATB((Q).y, a1) GATB((Q).z, a2) GATB((Q).w, a3)

    int j = start;
    for (; j + 4 < end; j += 8) {
        uint4 eA = *(const uint4*)&ew[j];
        uint4 eB = *(const uint4*)&ew[j + 4];
        GATB4(eA)
        GATB4(eB)
    }
    if (j < end) {
        uint4 eA = *(const uint4*)&ew[j];
        GATB4(eA)
    }
    #undef GATB4
    #undef GATB

    const float inv = invden[v];
    float* __restrict__ op = out + (size_t)v * HID + chunk * 32 + q * 8;
    const float* __restrict__ bp = bias + chunk * 32 + q * 8;
    float4 o0, o1;
    o0.x = fmaxf((a0[0]+a1[0]+a2[0]+a3[0]) * inv + bp[0], 0.f);
    o0.y = fmaxf((a0[1]+a1[1]+a2[1]+a3[1]) * inv + bp[1], 0.f);
    o0.z = fmaxf((a0[2]+a1[2]+a2[2]+a3[2]) * inv + bp[2], 0.f);
    o0.w = fmaxf((a0[3]+a1[3]+a2[3]+a3[3]) * inv + bp[3], 0.f);
    o1.x = fmaxf((a0[4]+a1[4]+a2[4]+a3[4]) * inv + bp[4], 0.f);
    o1.y = fmaxf((a0[5]+a1[5]+a2[5]+a3[5]) * inv + bp[5], 0.f);
    o1.z = fmaxf((a0[6]+a1[6]+a2[6]+a3[6]) * inv + bp[6], 0.f);
    o1.w = fmaxf((a0[7]+a1[7]+a2[7]+a3[7]) * inv + bp[7], 0.f);
    *(float4*)&op[0] = o0;
    *(float4*)&op[4] = o1;
}

// ---------------- layer-2 SpMM (f32 H, 16-feature chunks) ----------------
__global__ __launch_bounds__(256) void k_spmm_f32(
        const float* __restrict__ Hc, const unsigned* __restrict__ ew,
        const float* __restrict__ invden, const float* __restrict__ bias,
        const int* __restrict__ off, float* __restrict__ out, int n) {
    const int chunk = blockIdx.x & 3;             // NCH = 64/16 = 4
    const int v = (blockIdx.x >> 2) * 64 + (threadIdx.x >> 2);
    if (v >= n) return;
    const int q = threadIdx.x & 3;                // feature quad 0..3
    const int start = off[v], end = off[v + 1];
    const float* __restrict__ Hch = Hc + (size_t)chunk * (size_t)n * 16 + q * 4;

    float4 a0 = make_float4(0.f, 0.f, 0.f, 0.f);
    float4 a1 = make_float4(0.f, 0.f, 0.f, 0.f);
    float4 a2 = make_float4(0.f, 0.f, 0.f, 0.f);
    float4 a3 = make_float4(0.f, 0.f, 0.f, 0.f);

    #define GAT(E, A)                                                  \
        {                                                              \
            float w_ = __uint_as_float((E) << 16);                     \
            float4 h_ = *(const float4*)&Hch[(size_t)((E) >> 16) * 16];\
            A.x += w_ * h_.x; A.y += w_ * h_.y;                        \
            A.z += w_ * h_.z; A.w += w_ * h_.w;                        \
        }
    #define GAT4(Q) GAT((Q).x, a0) GAT((Q).y, a1) GAT((Q).z, a2) GAT((Q).w, a3)

    int j = start;
    for (; j + 4 < end; j += 8) {
        uint4 eA = *(const uint4*)&ew[j];
        uint4 eB = *(const uint4*)&ew[j + 4];
        GAT4(eA)
        GAT4(eB)
    }
    if (j < end) {
        uint4 eA = *(const uint4*)&ew[j];
        GAT4(eA)
    }
    #undef GAT4
    #undef GAT

    const float inv = invden[v];
    const float4 b = *(const float4*)&bias[chunk * 16 + q * 4];
    float4v o;
    o[0] = (a0.x + a1.x + a2.x + a3.x) * inv + b.x;
    o[1] = (a0.y + a1.y + a2.y + a3.y) * inv + b.y;
    o[2] = (a0.z + a1.z + a2.z + a3.z) * inv + b.z;
    o[3] = (a0.w + a1.w + a2.w + a3.w) * inv + b.w;
    // final output: pure write-stream -> nontemporal (don't evict H from L2)
    __builtin_nontemporal_store(o, (float4v*)&out[(size_t)v * OUT_CH + chunk * 16 + q * 4]);
}

// ---------------- launch ----------------

extern "C" void kernel_launch(void* const* d_in, const int* in_sizes, int n_in,
                              void* d_out, int out_size, void* d_ws, size_t ws_size,
                              hipStream_t stream) {
    const float* x     = (const float*)d_in[0];
    const int*   ei    = (const int*)d_in[1];
    const float* W1    = (const float*)d_in[2];
    const float* as1   = (const float*)d_in[3];
    const float* ad1   = (const float*)d_in[4];
    const float* b1    = (const float*)d_in[5];
    const float* W2    = (const float*)d_in[6];
    const float* as2   = (const float*)d_in[7];
    const float* ad2   = (const float*)d_in[8];
    const float* b2    = (const float*)d_in[9];
    float* out = (float*)d_out;

    const int Nn = N_NODES, E = N_EDGES, ET = N_TOT_EDGES;

    // workspace carve-up (256B aligned)
    char* ws = (char*)d_ws;
    size_t o = 0;
    auto carve = [&](size_t bytes) { char* p = ws + o; o = (o + bytes + 255) & ~(size_t)255; return p; };
    int*            off  = (int*)carve((Nn + 1) * sizeof(int));
    int*            cnt  = (int*)carve(Nn * sizeof(int));
    int*            cur  = (int*)carve(Nn * sizeof(int));
    int*            bsum = (int*)carve(256 * sizeof(int));
    int*            csr  = (int*)carve((size_t)ET_PAD * sizeof(int));
    unsigned*       ew   = (unsigned*)carve((size_t)ET_PAD * sizeof(unsigned));
    unsigned short* h1b  = (unsigned short*)carve((size_t)Nn * HID * sizeof(unsigned short));
    float*          h2   = (float*)carve((size_t)Nn * OUT_CH * sizeof(float));
    float*          alsA = (float*)carve(Nn * sizeof(float));
    float*          aldA = (float*)carve(Nn * sizeof(float));
    float*          alsB = (float*)carve(Nn * sizeof(float));
    float*          aldB = (float*)carve(Nn * sizeof(float));
    float*          invd = (float*)carve(Nn * sizeof(float));
    float*          y1   = (float*)carve((size_t)Nn * HID * sizeof(float));

    const int nbN  = (Nn + 255) / 256;
    const int nbE  = (E + 255) / 256;
    const int nbET = (ET + 255) / 256;

    // CSR build (padded-to-4 segments)
    k_init<<<nbN, 256, 0, stream>>>(cnt, cur, alsA, aldA, alsB, aldB, Nn);
    k_count<<<nbE, 256, 0, stream>>>(ei + E, cnt, E);
    k_scan1<<<nbN, 256, 0, stream>>>(cnt, off, bsum, Nn);
    k_scan2<<<1, 256, 0, stream>>>(bsum, nbN);
    k_scan3<<<nbN, 256, 0, stream>>>(off, bsum, Nn);
    k_fill<<<nbET, 256, 0, stream>>>(ei, off, cur, csr, E, Nn);
    hipMemsetAsync(ew, 0, (size_t)ET_PAD * sizeof(unsigned), stream);  // pads -> (src=0, w=0)

    const int nbEW  = (Nn + 15) / 16;
    const int nbN64 = (Nn + 63) / 64;

    // layer 1: H in bf16 (32-feat chunks, 4 spmm passes)
    gemm_att<HID, true><<<nbN64 * (HID / 64), 256, 0, stream>>>(
        x, W1, as1, ad1, h1b, alsA, aldA, Nn);
    k_edgew<<<nbEW, 256, 0, stream>>>(alsA, aldA, off, cnt, csr, ew, invd, Nn);
    k_spmm_bf16<<<nbN64 * 4, 256, 0, stream>>>(h1b, ew, invd, b1, off, y1, Nn);

    // layer 2: H in f32 (16-feat chunks, 4 spmm passes)
    gemm_att<OUT_CH, false><<<nbN64 * (OUT_CH / 64), 256, 0, stream>>>(
        y1, W2, as2, ad2, h2, alsB, aldB, Nn);
    k_edgew<<<nbEW, 256, 0, stream>>>(alsB, aldB, off, cnt, csr, ew, invd, Nn);
    k_spmm_f32<<<nbN64 * 4, 256, 0, stream>>>(h2, ew, invd, b2, off, out, Nn);
}

// Round 14
// 202.041 us; speedup vs baseline: 1.1927x; 1.1927x over previous
//
#include <hip/hip_runtime.h>
#include <hip/hip_bf16.h>

#define N_NODES 50000
#define IN_CH 128
#define HID 128
#define OUT_CH 64
#define N_EDGES 800000
#define N_TOT_EDGES (N_EDGES + N_NODES)         // + self loops
#define ET_PAD (N_TOT_EDGES + 3 * N_NODES)      // worst-case pad-to-4 per node
#define MPAD 50048                              // 782 * 64 (gemm row-block pad)

typedef float float4v __attribute__((ext_vector_type(4)));
typedef __attribute__((ext_vector_type(8))) short bf16x8;
typedef __attribute__((ext_vector_type(4))) float f32x4;

__device__ __forceinline__ unsigned bf16_rne(float f) {
    unsigned u = __float_as_uint(f);
    return (u + 0x7fffu + ((u >> 16) & 1u)) >> 16;
}
__device__ __forceinline__ unsigned pack2(float a, float b) {
    return bf16_rne(a) | (bf16_rne(b) << 16);
}

// ---------------- CSR build ----------------

__global__ void k_init_cnt(int* cnt, int* cur, int n) {
    int i = blockIdx.x * 256 + threadIdx.x;
    if (i < n) { cnt[i] = 1; cur[i] = 0; }   // self-loop contributes 1
}

__global__ void k_count(const int* __restrict__ dst_row, int* __restrict__ cnt, int e) {
    int i = blockIdx.x * 256 + threadIdx.x;
    if (i < e) atomicAdd(&cnt[dst_row[i]], 1);
}

__global__ void k_scan1(const int* __restrict__ cnt, int* __restrict__ off,
                        int* __restrict__ bsum, int n) {
    __shared__ int s[256];
    int t = threadIdx.x;
    int i = blockIdx.x * 256 + t;
    int v = (i < n) ? ((cnt[i] + 3) & ~3) : 0;   // pad segments to 4
    s[t] = v;
    __syncthreads();
    for (int d = 1; d < 256; d <<= 1) {
        int x = (t >= d) ? s[t - d] : 0;
        __syncthreads();
        s[t] += x;
        __syncthreads();
    }
    if (i < n) off[i + 1] = s[t];
    if (t == 255) bsum[blockIdx.x] = s[255];
}

__global__ void k_scan2(int* __restrict__ bsum, int nb) {  // single block, nb <= 256
    __shared__ int s[256];
    int t = threadIdx.x;
    int v = (t < nb) ? bsum[t] : 0;
    s[t] = v;
    __syncthreads();
    for (int d = 1; d < 256; d <<= 1) {
        int x = (t >= d) ? s[t - d] : 0;
        __syncthreads();
        s[t] += x;
        __syncthreads();
    }
    if (t < nb) bsum[t] = s[t] - v;  // exclusive prefix
}

__global__ void k_scan3(int* __restrict__ off, const int* __restrict__ bsum, int n) {
    int i = blockIdx.x * 256 + threadIdx.x;
    if (i < n) off[i + 1] += bsum[blockIdx.x];
    if (i == 0) off[0] = 0;
}

__global__ void k_fill(const int* __restrict__ ei, const int* __restrict__ off,
                       int* __restrict__ cur, int* __restrict__ csr, int e, int n) {
    int i = blockIdx.x * 256 + threadIdx.x;
    if (i >= e + n) return;
    int src, dst;
    if (i < e) { src = ei[i]; dst = ei[e + i]; }
    else       { src = dst = i - e; }
    int pos = off[dst] + atomicAdd(&cur[dst], 1);
    csr[pos] = src;
}

// ---------------- f32 -> bf16 tiled conversions for MFMA ----------------
// Xb layout: [row>>4][kg 0..15][row&15][8] bf16 (kg = k/8). A-frag for MFMA
// k-step s, lane l = Xb[rb>>4][s*4 + (l>>4)][l&15][0..8) -> one fully-coalesced
// 1KB load per wave. Pad rows (>= M) written as zeros.
__global__ __launch_bounds__(256) void k_cvtX(const float* __restrict__ X,
                                              unsigned short* __restrict__ Xb, int M) {
    const int t = threadIdx.x;
    const int kg = t >> 4, rl = t & 15;
    const int row = blockIdx.x * 16 + rl;
    float4 a = make_float4(0.f, 0.f, 0.f, 0.f), b = a;
    if (row < M) {
        a = *(const float4*)&X[(size_t)row * 128 + kg * 8];
        b = *(const float4*)&X[(size_t)row * 128 + kg * 8 + 4];
    }
    uint4 p;
    p.x = pack2(a.x, a.y); p.y = pack2(a.z, a.w);
    p.z = pack2(b.x, b.y); p.w = pack2(b.z, b.w);
    *(uint4*)&Xb[(size_t)blockIdx.x * 2048 + kg * 128 + rl * 8] = p;
}

// Wl layout: [kg][col][8] bf16. B-frag for k-step s, lane l =
// Wl[s*4 + (l>>4)][cbase + (l&15)][0..8) — same k-map as A (k-permutation
// invariance: any consistent kmap on BOTH A and B gives the exact product).
template<int N>
__global__ __launch_bounds__(256) void k_cvtW(const float* __restrict__ W,
                                              unsigned short* __restrict__ Wl) {
    const int tg = blockIdx.x * 256 + threadIdx.x;
    if (tg >= 16 * N) return;
    const int kg = tg / N, col = tg & (N - 1);
    float v[8];
    #pragma unroll
    for (int j = 0; j < 8; ++j) v[j] = W[(size_t)(kg * 8 + j) * N + col];
    uint4 p;
    p.x = pack2(v[0], v[1]); p.y = pack2(v[2], v[3]);
    p.z = pack2(v[4], v[5]); p.w = pack2(v[6], v[7]);
    *(uint4*)&Wl[(size_t)tg * 8] = p;
}

// ---------------- MFMA GEMM (h = X @ W) + fused attention dots ----------------
// Block = 256 thr = 4 waves; wave = 16 rows x ALL N cols (so attention dots
// need no atomics). Per wave: 4 k-steps x (N/16) MFMA_16x16x32_bf16, A-frags
// from global (coalesced 1KB/step, X read once), B-frags from LDS W (32/16KB,
// conflict-free: 16 lanes stride 16B, upper lanes broadcast).
// C/D layout (guide-verified m89/m91): col = lane&15, row = (lane>>4)*4 + reg.
template<int N, bool BF16OUT>
__global__ __launch_bounds__(256) void gemm_mfma(
        const unsigned short* __restrict__ Xb, const unsigned short* __restrict__ Wlg,
        const float* __restrict__ asrc, const float* __restrict__ adst,
        void* __restrict__ HcV, float* __restrict__ als, float* __restrict__ ald,
        int M) {
    constexpr int NF = N / 16;
    __shared__ unsigned short Wl[16 * N * 8];
    const int t = threadIdx.x;
    for (int i = t; i < N * 16; i += 256)
        ((uint4*)Wl)[i] = ((const uint4*)Wlg)[i];
    __syncthreads();

    const int lane = t & 63, w = t >> 6;
    const int rb = blockIdx.x * 64 + w * 16;
    const int cl = lane & 15, g = lane >> 4;
    const unsigned short* __restrict__ Abase = Xb + (size_t)(rb >> 4) * 2048 + cl * 8;

    f32x4 acc[NF];
    #pragma unroll
    for (int n = 0; n < NF; ++n) acc[n] = (f32x4){0.f, 0.f, 0.f, 0.f};

    #pragma unroll
    for (int s = 0; s < 4; ++s) {
        bf16x8 af = *(const bf16x8*)(Abase + (s * 4 + g) * 128);
        #pragma unroll
        for (int n = 0; n < NF; ++n) {
            bf16x8 bf = *(const bf16x8*)(Wl + ((s * 4 + g) * N + n * 16 + cl) * 8);
            acc[n] = __builtin_amdgcn_mfma_f32_16x16x32_bf16(af, bf, acc[n], 0, 0, 0);
        }
    }

    float asv[NF], adv[NF];
    #pragma unroll
    for (int n = 0; n < NF; ++n) {
        asv[n] = asrc[n * 16 + cl];
        adv[n] = adst[n * 16 + cl];
    }

    #pragma unroll
    for (int r = 0; r < 4; ++r) {
        float ps = 0.f, pd = 0.f;
        #pragma unroll
        for (int n = 0; n < NF; ++n) {
            ps += acc[n][r] * asv[n];
            pd += acc[n][r] * adv[n];
        }
        #pragma unroll
        for (int mask = 1; mask < 16; mask <<= 1) {
            ps += __shfl_xor(ps, mask);
            pd += __shfl_xor(pd, mask);
        }
        const int row = rb + g * 4 + r;
        if (cl == 0 && row < M) { als[row] = ps; ald[row] = pd; }
    }

    #pragma unroll
    for (int r = 0; r < 4; ++r) {
        const int row = rb + g * 4 + r;
        if (row >= M) continue;
        if (BF16OUT) {
            unsigned short* Hb = (unsigned short*)HcV;
            #pragma unroll
            for (int n = 0; n < NF; ++n)
                Hb[(size_t)(n >> 1) * (size_t)M * 32 + (size_t)row * 32
                   + (n & 1) * 16 + cl] = (unsigned short)bf16_rne(acc[n][r]);
        } else {
            float* Hc = (float*)HcV;
            #pragma unroll
            for (int n = 0; n < NF; ++n)
                Hc[(size_t)n * (size_t)M * 16 + (size_t)row * 16 + cl] = acc[n][r];
        }
    }
}

// ---------------- edge weights: packed u32 = (src<<16) | bf16(exp(leaky(e))) ----
__global__ __launch_bounds__(256) void k_edgew(
        const float* __restrict__ als, const float* __restrict__ ald,
        const int* __restrict__ off, const int* __restrict__ cnt,
        const int* __restrict__ csr,
        unsigned* __restrict__ ew, float* __restrict__ invden, int n) {
    const int fl = threadIdx.x & 15;
    const int v = blockIdx.x * 16 + (threadIdx.x >> 4);
    if (v >= n) return;
    const int start = off[v], end = start + cnt[v];
    const float aldv = ald[v];
    float s = 0.f;
    for (int j = start + fl; j < end; j += 16) {
        int src = __builtin_nontemporal_load(&csr[j]);
        float e = als[src] + aldv;
        e = e > 0.f ? e : 0.2f * e;
        unsigned r = bf16_rne(__expf(e));
        ew[j] = ((unsigned)src << 16) | r;
        s += __uint_as_float(r << 16);
    }
    #pragma unroll
    for (int d = 1; d < 16; d <<= 1) s += __shfl_xor(s, d);
    if (fl == 0) invden[v] = 1.f / (s + 1e-16f);
}

// ---------------- layer-1 SpMM (bf16 H, 32-feature chunks, 4 passes) ------------
// Writes y1 DIRECTLY in the Xb-tiled bf16 layout gemm2 consumes (one uint4
// store/thread; no separate conversion pass, half the write traffic of f32).
__global__ __launch_bounds__(256) void k_spmm_bf16(
        const unsigned short* __restrict__ Hb, const unsigned* __restrict__ ew,
        const float* __restrict__ invden, const float* __restrict__ bias,
        const int* __restrict__ off, unsigned short* __restrict__ Xb2, int n) {
    const int chunk = blockIdx.x & 3;             // NCH = 128/32 = 4
    const int v = (blockIdx.x >> 2) * 64 + (threadIdx.x >> 2);
    if (v >= n) return;
    const int q = threadIdx.x & 3;                // 8-feat group 0..3
    const int start = off[v], end = off[v + 1];   // padded: multiple of 4, >= 4
    const unsigned short* __restrict__ Hch = Hb + (size_t)chunk * (size_t)n * 32 + q * 8;

    float a0[8] = {}, a1[8] = {}, a2[8] = {}, a3[8] = {};

    #define GATB(E, A)                                                   \
        {                                                                \
            float w_ = __uint_as_float((E) << 16);                       \
            uint4 h_ = *(const uint4*)&Hch[(size_t)((E) >> 16) * 32];    \
            A[0] += w_ * __uint_as_float(h_.x << 16);                    \
            A[1] += w_ * __uint_as_float(h_.x & 0xffff0000u);            \
            A[2] += w_ * __uint_as_float(h_.y << 16);                    \
            A[3] += w_ * __uint_as_float(h_.y & 0xffff0000u);            \
            A[4] += w_ * __uint_as_float(h_.z << 16);                    \
            A[5] += w_ * __uint_as_float(h_.z & 0xffff0000u);            \
            A[6] += w_ * __uint_as_float(h_.w << 16);                    \
            A[7] += w_ * __uint_as_float(h_.w & 0xffff0000u);            \
        }
    #define GATB4(Q) GATB((Q).x, a0) GATB((Q).y, a1) GATB((Q).z, a2) GATB((Q).w, a3)

    int j = start;
    for (; j + 4 < end; j += 8) {
        uint4 eA = *(const uint4*)&ew[j];
        uint4 eB = *(const uint4*)&ew[j + 4];
        GATB4(eA)
        GATB4(eB)
    }
    if (j < end) {
        uint4 eA = *(const uint4*)&ew[j];
        GATB4(eA)
    }
    #undef GATB4
    #undef GATB

    const float inv = invden[v];
    const float* __restrict__ bp = bias + chunk * 32 + q * 8;
    float s[8];
    #pragma unroll
    for (int i = 0; i < 8; ++i)
        s[i] = fmaxf((a0[i] + a1[i] + a2[i] + a3[i]) * inv + bp[i], 0.f);

    const int kg = chunk * 4 + q;
    uint4 p;
    p.x = pack2(s[0], s[1]); p.y = pack2(s[2], s[3]);
    p.z = pack2(s[4], s[5]); p.w = pack2(s[6], s[7]);
    *(uint4*)&Xb2[(size_t)(v >> 4) * 2048 + kg * 128 + (v & 15) * 8] = p;
}

// ---------------- layer-2 SpMM (f32 H, 16-feature chunks) ----------------
__global__ __launch_bounds__(256) void k_spmm_f32(
        const float* __restrict__ Hc, const unsigned* __restrict__ ew,
        const float* __restrict__ invden, const float* __restrict__ bias,
        const int* __restrict__ off, float* __restrict__ out, int n) {
    const int chunk = blockIdx.x & 3;             // NCH = 64/16 = 4
    const int v = (blockIdx.x >> 2) * 64 + (threadIdx.x >> 2);
    if (v >= n) return;
    const int q = threadIdx.x & 3;                // feature quad 0..3
    const int start = off[v], end = off[v + 1];
    const float* __restrict__ Hch = Hc + (size_t)chunk * (size_t)n * 16 + q * 4;

    float4 a0 = make_float4(0.f, 0.f, 0.f, 0.f);
    float4 a1 = make_float4(0.f, 0.f, 0.f, 0.f);
    float4 a2 = make_float4(0.f, 0.f, 0.f, 0.f);
    float4 a3 = make_float4(0.f, 0.f, 0.f, 0.f);

    #define GAT(E, A)                                                  \
        {                                                              \
            float w_ = __uint_as_float((E) << 16);                     \
            float4 h_ = *(const float4*)&Hch[(size_t)((E) >> 16) * 16];\
            A.x += w_ * h_.x; A.y += w_ * h_.y;                        \
            A.z += w_ * h_.z; A.w += w_ * h_.w;                        \
        }
    #define GAT4(Q) GAT((Q).x, a0) GAT((Q).y, a1) GAT((Q).z, a2) GAT((Q).w, a3)

    int j = start;
    for (; j + 4 < end; j += 8) {
        uint4 eA = *(const uint4*)&ew[j];
        uint4 eB = *(const uint4*)&ew[j + 4];
        GAT4(eA)
        GAT4(eB)
    }
    if (j < end) {
        uint4 eA = *(const uint4*)&ew[j];
        GAT4(eA)
    }
    #undef GAT4
    #undef GAT

    const float inv = invden[v];
    const float4 b = *(const float4*)&bias[chunk * 16 + q * 4];
    float4v o;
    o[0] = (a0.x + a1.x + a2.x + a3.x) * inv + b.x;
    o[1] = (a0.y + a1.y + a2.y + a3.y) * inv + b.y;
    o[2] = (a0.z + a1.z + a2.z + a3.z) * inv + b.z;
    o[3] = (a0.w + a1.w + a2.w + a3.w) * inv + b.w;
    __builtin_nontemporal_store(o, (float4v*)&out[(size_t)v * OUT_CH + chunk * 16 + q * 4]);
}

// ---------------- launch ----------------

extern "C" void kernel_launch(void* const* d_in, const int* in_sizes, int n_in,
                              void* d_out, int out_size, void* d_ws, size_t ws_size,
                              hipStream_t stream) {
    const float* x     = (const float*)d_in[0];
    const int*   ei    = (const int*)d_in[1];
    const float* W1    = (const float*)d_in[2];
    const float* as1   = (const float*)d_in[3];
    const float* ad1   = (const float*)d_in[4];
    const float* b1    = (const float*)d_in[5];
    const float* W2    = (const float*)d_in[6];
    const float* as2   = (const float*)d_in[7];
    const float* ad2   = (const float*)d_in[8];
    const float* b2    = (const float*)d_in[9];
    float* out = (float*)d_out;

    const int Nn = N_NODES, E = N_EDGES, ET = N_TOT_EDGES;

    // workspace carve-up (256B aligned)
    char* ws = (char*)d_ws;
    size_t o = 0;
    auto carve = [&](size_t bytes) { char* p = ws + o; o = (o + bytes + 255) & ~(size_t)255; return p; };
    int*            off  = (int*)carve((Nn + 1) * sizeof(int));
    int*            cnt  = (int*)carve(Nn * sizeof(int));
    int*            cur  = (int*)carve(Nn * sizeof(int));
    int*            bsum = (int*)carve(256 * sizeof(int));
    int*            csr  = (int*)carve((size_t)ET_PAD * sizeof(int));
    unsigned*       ew   = (unsigned*)carve((size_t)ET_PAD * sizeof(unsigned));
    unsigned short* h1b  = (unsigned short*)carve((size_t)Nn * HID * sizeof(unsigned short));
    float*          h2   = (float*)carve((size_t)Nn * OUT_CH * sizeof(float));
    unsigned short* Xb1  = (unsigned short*)carve((size_t)MPAD * 128 * sizeof(unsigned short));
    unsigned short* Xb2  = (unsigned short*)carve((size_t)MPAD * 128 * sizeof(unsigned short));
    unsigned short* Wl1  = (unsigned short*)carve(16 * 128 * 8 * sizeof(unsigned short));
    unsigned short* Wl2  = (unsigned short*)carve(16 * 64 * 8 * sizeof(unsigned short));
    float*          als  = (float*)carve(Nn * sizeof(float));
    float*          ald  = (float*)carve(Nn * sizeof(float));
    float*          invd = (float*)carve(Nn * sizeof(float));

    const int nbN  = (Nn + 255) / 256;
    const int nbE  = (E + 255) / 256;
    const int nbET = (ET + 255) / 256;

    // CSR build (padded-to-4 segments)
    k_init_cnt<<<nbN, 256, 0, stream>>>(cnt, cur, Nn);
    k_count<<<nbE, 256, 0, stream>>>(ei + E, cnt, E);
    k_scan1<<<nbN, 256, 0, stream>>>(cnt, off, bsum, Nn);
    k_scan2<<<1, 256, 0, stream>>>(bsum, nbN);
    k_scan3<<<nbN, 256, 0, stream>>>(off, bsum, Nn);
    k_fill<<<nbET, 256, 0, stream>>>(ei, off, cur, csr, E, Nn);
    hipMemsetAsync(ew, 0, (size_t)ET_PAD * sizeof(unsigned), stream);  // pads -> (src=0, w=0)

    // bf16 conversions for MFMA
    k_cvtX<<<MPAD / 16, 256, 0, stream>>>(x, Xb1, Nn);
    k_cvtW<128><<<(16 * 128) / 256, 256, 0, stream>>>(W1, Wl1);
    k_cvtW<64><<<(16 * 64) / 256, 256, 0, stream>>>(W2, Wl2);

    const int nbEW   = (Nn + 15) / 16;
    const int nbN64  = (Nn + 63) / 64;
    const int nbGEMM = MPAD / 64;   // 782

    // layer 1
    gemm_mfma<HID, true><<<nbGEMM, 256, 0, stream>>>(
        Xb1, Wl1, as1, ad1, h1b, als, ald, Nn);
    k_edgew<<<nbEW, 256, 0, stream>>>(als, ald, off, cnt, csr, ew, invd, Nn);
    k_spmm_bf16<<<nbN64 * 4, 256, 0, stream>>>(h1b, ew, invd, b1, off, Xb2, Nn);

    // layer 2
    gemm_mfma<OUT_CH, false><<<nbGEMM, 256, 0, stream>>>(
        Xb2, Wl2, as2, ad2, h2, als, ald, Nn);
    k_edgew<<<nbEW, 256, 0, stream>>>(als, ald, off, cnt, csr, ew, invd, Nn);
    k_spmm_f32<<<nbN64 * 4, 256, 0, stream>>>(h2, ew, invd, b2, off, out, Nn);
}

// Round 15
// 173.686 us; speedup vs baseline: 1.3874x; 1.1633x over previous
//
#include <hip/hip_runtime.h>
#include <hip/hip_bf16.h>

#define N_NODES 50000
#define IN_CH 128
#define HID 128
#define OUT_CH 64
#define N_EDGES 800000
#define N_TOT_EDGES (N_EDGES + N_NODES)         // + self loops
#define ET_PAD (N_TOT_EDGES + 3 * N_NODES)      // worst-case pad-to-4 per node
#define MPAD 50048                              // 782 * 64 (gemm row-block pad)

typedef float float4v __attribute__((ext_vector_type(4)));
typedef unsigned uint4v __attribute__((ext_vector_type(4)));
typedef __attribute__((ext_vector_type(8))) short bf16x8;
typedef __attribute__((ext_vector_type(4))) float f32x4;

__device__ __forceinline__ unsigned bf16_rne(float f) {
    unsigned u = __float_as_uint(f);
    return (u + 0x7fffu + ((u >> 16) & 1u)) >> 16;
}
__device__ __forceinline__ unsigned pack2(float a, float b) {
    return bf16_rne(a) | (bf16_rne(b) << 16);
}

// ---------------- CSR build ----------------

__global__ void k_init_cnt(int* cnt, int n) {
    int i = blockIdx.x * 256 + threadIdx.x;
    if (i < n) cnt[i] = 1;   // self-loop reserves slot 0 of each segment
}

// count + RANK capture: rank[i] = old count (1..deg). The atomic's return
// value makes the fill pass atomic-free (r14 post-mortem: fill's 850K
// device-scope atomics + scatter were the top dispatch at 42us).
__global__ void k_count(const int* __restrict__ dst_row, int* __restrict__ cnt,
                        unsigned short* __restrict__ rank, int e) {
    int i = blockIdx.x * 256 + threadIdx.x;
    if (i < e) rank[i] = (unsigned short)atomicAdd(&cnt[dst_row[i]], 1);
}

// inclusive scan of PADDED counts -> off[i+1]; per-block sums to bsum.
__global__ void k_scan1(const int* __restrict__ cnt, int* __restrict__ off,
                        int* __restrict__ bsum, int n) {
    __shared__ int s[256];
    int t = threadIdx.x;
    int i = blockIdx.x * 256 + t;
    int v = (i < n) ? ((cnt[i] + 3) & ~3) : 0;   // pad segments to 4
    s[t] = v;
    __syncthreads();
    for (int d = 1; d < 256; d <<= 1) {
        int x = (t >= d) ? s[t - d] : 0;
        __syncthreads();
        s[t] += x;
        __syncthreads();
    }
    if (i < n) off[i + 1] = s[t];
    if (t == 255) bsum[blockIdx.x] = s[255];
}

__global__ void k_scan2(int* __restrict__ bsum, int nb) {  // single block, nb <= 256
    __shared__ int s[256];
    int t = threadIdx.x;
    int v = (t < nb) ? bsum[t] : 0;
    s[t] = v;
    __syncthreads();
    for (int d = 1; d < 256; d <<= 1) {
        int x = (t >= d) ? s[t - d] : 0;
        __syncthreads();
        s[t] += x;
        __syncthreads();
    }
    if (t < nb) bsum[t] = s[t] - v;  // exclusive prefix
}

__global__ void k_scan3(int* __restrict__ off, const int* __restrict__ bsum, int n) {
    int i = blockIdx.x * 256 + threadIdx.x;
    if (i < n) off[i + 1] += bsum[blockIdx.x];
    if (i == 0) off[0] = 0;
}

// atomic-free fill: edge i -> csr[off[dst] + rank[i]]; self-loop v -> slot 0.
__global__ void k_fill2(const int* __restrict__ ei, const int* __restrict__ off,
                        const unsigned short* __restrict__ rank,
                        int* __restrict__ csr, int e, int n) {
    int i = blockIdx.x * 256 + threadIdx.x;
    if (i < e) {
        int src = ei[i], dst = ei[e + i];
        csr[off[dst] + rank[i]] = src;
    } else if (i < e + n) {
        int v = i - e;
        csr[off[v]] = v;
    }
}

// ---------------- f32 -> bf16 tiled conversions for MFMA ----------------
// Xb layout: [row>>4][kg 0..15][row&15][8] bf16 (kg = k/8).
__global__ __launch_bounds__(256) void k_cvtX(const float* __restrict__ X,
                                              unsigned short* __restrict__ Xb, int M) {
    const int t = threadIdx.x;
    const int kg = t >> 4, rl = t & 15;
    const int row = blockIdx.x * 16 + rl;
    float4 a = make_float4(0.f, 0.f, 0.f, 0.f), b = a;
    if (row < M) {
        a = *(const float4*)&X[(size_t)row * 128 + kg * 8];
        b = *(const float4*)&X[(size_t)row * 128 + kg * 8 + 4];
    }
    uint4 p;
    p.x = pack2(a.x, a.y); p.y = pack2(a.z, a.w);
    p.z = pack2(b.x, b.y); p.w = pack2(b.z, b.w);
    *(uint4*)&Xb[(size_t)blockIdx.x * 2048 + kg * 128 + rl * 8] = p;
}

// Wl layout: [kg][col][8] bf16 (same k-map as A: k-permutation invariance).
template<int N>
__global__ __launch_bounds__(256) void k_cvtW(const float* __restrict__ W,
                                              unsigned short* __restrict__ Wl) {
    const int tg = blockIdx.x * 256 + threadIdx.x;
    if (tg >= 16 * N) return;
    const int kg = tg / N, col = tg & (N - 1);
    float v[8];
    #pragma unroll
    for (int j = 0; j < 8; ++j) v[j] = W[(size_t)(kg * 8 + j) * N + col];
    uint4 p;
    p.x = pack2(v[0], v[1]); p.y = pack2(v[2], v[3]);
    p.z = pack2(v[4], v[5]); p.w = pack2(v[6], v[7]);
    *(uint4*)&Wl[(size_t)tg * 8] = p;
}

// ---------------- MFMA GEMM (h = X @ W) + fused attention dots ----------------
// Block = 4 waves; wave = 16 rows x ALL N cols (attention dots atomic-free).
// C/D layout (guide-verified m89/m91): col = lane&15, row = (lane>>4)*4 + reg.
template<int N, bool BF16OUT>
__global__ __launch_bounds__(256) void gemm_mfma(
        const unsigned short* __restrict__ Xb, const unsigned short* __restrict__ Wlg,
        const float* __restrict__ asrc, const float* __restrict__ adst,
        void* __restrict__ HcV, float* __restrict__ als, float* __restrict__ ald,
        int M) {
    constexpr int NF = N / 16;
    __shared__ unsigned short Wl[16 * N * 8];
    const int t = threadIdx.x;
    for (int i = t; i < N * 16; i += 256)
        ((uint4*)Wl)[i] = ((const uint4*)Wlg)[i];
    __syncthreads();

    const int lane = t & 63, w = t >> 6;
    const int rb = blockIdx.x * 64 + w * 16;
    const int cl = lane & 15, g = lane >> 4;
    const unsigned short* __restrict__ Abase = Xb + (size_t)(rb >> 4) * 2048 + cl * 8;

    f32x4 acc[NF];
    #pragma unroll
    for (int n = 0; n < NF; ++n) acc[n] = (f32x4){0.f, 0.f, 0.f, 0.f};

    #pragma unroll
    for (int s = 0; s < 4; ++s) {
        bf16x8 af = *(const bf16x8*)(Abase + (s * 4 + g) * 128);
        #pragma unroll
        for (int n = 0; n < NF; ++n) {
            bf16x8 bf = *(const bf16x8*)(Wl + ((s * 4 + g) * N + n * 16 + cl) * 8);
            acc[n] = __builtin_amdgcn_mfma_f32_16x16x32_bf16(af, bf, acc[n], 0, 0, 0);
        }
    }

    float asv[NF], adv[NF];
    #pragma unroll
    for (int n = 0; n < NF; ++n) {
        asv[n] = asrc[n * 16 + cl];
        adv[n] = adst[n * 16 + cl];
    }

    #pragma unroll
    for (int r = 0; r < 4; ++r) {
        float ps = 0.f, pd = 0.f;
        #pragma unroll
        for (int n = 0; n < NF; ++n) {
            ps += acc[n][r] * asv[n];
            pd += acc[n][r] * adv[n];
        }
        #pragma unroll
        for (int mask = 1; mask < 16; mask <<= 1) {
            ps += __shfl_xor(ps, mask);
            pd += __shfl_xor(pd, mask);
        }
        const int row = rb + g * 4 + r;
        if (cl == 0 && row < M) { als[row] = ps; ald[row] = pd; }
    }

    #pragma unroll
    for (int r = 0; r < 4; ++r) {
        const int row = rb + g * 4 + r;
        if (row >= M) continue;
        if (BF16OUT) {
            unsigned short* Hb = (unsigned short*)HcV;
            #pragma unroll
            for (int n = 0; n < NF; ++n)
                Hb[(size_t)(n >> 1) * (size_t)M * 32 + (size_t)row * 32
                   + (n & 1) * 16 + cl] = (unsigned short)bf16_rne(acc[n][r]);
        } else {
            float* Hc = (float*)HcV;
            #pragma unroll
            for (int n = 0; n < NF; ++n)
                Hc[(size_t)n * (size_t)M * 16 + (size_t)row * 16 + cl] = acc[n][r];
        }
    }
}

// ---------------- edge weights: packed u32 = (src<<16) | bf16(exp(leaky(e))) ----
__global__ __launch_bounds__(256) void k_edgew(
        const float* __restrict__ als, const float* __restrict__ ald,
        const int* __restrict__ off, const int* __restrict__ cnt,
        const int* __restrict__ csr,
        unsigned* __restrict__ ew, float* __restrict__ invden, int n) {
    const int fl = threadIdx.x & 15;
    const int v = blockIdx.x * 16 + (threadIdx.x >> 4);
    if (v >= n) return;
    const int start = off[v], end = start + cnt[v];
    const float aldv = ald[v];
    float s = 0.f;
    for (int j = start + fl; j < end; j += 16) {
        int src = __builtin_nontemporal_load(&csr[j]);
        float e = als[src] + aldv;
        e = e > 0.f ? e : 0.2f * e;
        unsigned r = bf16_rne(__expf(e));
        ew[j] = ((unsigned)src << 16) | r;
        s += __uint_as_float(r << 16);
    }
    #pragma unroll
    for (int d = 1; d < 16; d <<= 1) s += __shfl_xor(s, d);
    if (fl == 0) invden[v] = 1.f / (s + 1e-16f);
}

// ---------------- layer-1 SpMM (bf16 H, 32-feature chunks, 4 passes) ------------
// Writes y1 DIRECTLY in the Xb-tiled bf16 layout gemm2 consumes; nt store
// (pure write-stream -> don't evict the L2-pinned H slice).
__global__ __launch_bounds__(256) void k_spmm_bf16(
        const unsigned short* __restrict__ Hb, const unsigned* __restrict__ ew,
        const float* __restrict__ invden, const float* __restrict__ bias,
        const int* __restrict__ off, unsigned short* __restrict__ Xb2, int n) {
    const int chunk = blockIdx.x & 3;             // NCH = 128/32 = 4
    const int v = (blockIdx.x >> 2) * 64 + (threadIdx.x >> 2);
    if (v >= n) return;
    const int q = threadIdx.x & 3;                // 8-feat group 0..3
    const int start = off[v], end = off[v + 1];   // padded: multiple of 4, >= 4
    const unsigned short* __restrict__ Hch = Hb + (size_t)chunk * (size_t)n * 32 + q * 8;

    float a0[8] = {}, a1[8] = {}, a2[8] = {}, a3[8] = {};

    #define GATB(E, A)                                                   \
        {                                                                \
            float w_ = __uint_as_float((E) << 16);                       \
            uint4 h_ = *(const uint4*)&Hch[(size_t)((E) >> 16) * 32];    \
            A[0] += w_ * __uint_as_float(h_.x << 16);                    \
            A[1] += w_ * __uint_as_float(h_.x & 0xffff0000u);            \
            A[2] += w_ * __uint_as_float(h_.y << 16);                    \
            A[3] += w_ * __uint_as_float(h_.y & 0xffff0000u);            \
            A[4] += w_ * __uint_as_float(h_.z << 16);                    \
            A[5] += w_ * __uint_as_float(h_.z & 0xffff0000u);            \
            A[6] += w_ * __uint_as_float(h_.w << 16);                    \
            A[7] += w_ * __uint_as_float(h_.w & 0xffff0000u);            \
        }
    #define GATB4(Q) GATB((Q).x, a0) GATB((Q).y, a1) GATB((Q).z, a2) GATB((Q).w, a3)

    int j = start;
    for (; j + 4 < end; j += 8) {
        uint4 eA = *(const uint4*)&ew[j];
        uint4 eB = *(const uint4*)&ew[j + 4];
        GATB4(eA)
        GATB4(eB)
    }
    if (j < end) {
        uint4 eA = *(const uint4*)&ew[j];
        GATB4(eA)
    }
    #undef GATB4
    #undef GATB

    const float inv = invden[v];
    const float* __restrict__ bp = bias + chunk * 32 + q * 8;
    float s[8];
    #pragma unroll
    for (int i = 0; i < 8; ++i)
        s[i] = fmaxf((a0[i] + a1[i] + a2[i] + a3[i]) * inv + bp[i], 0.f);

    const int kg = chunk * 4 + q;
    uint4v p;
    p[0] = pack2(s[0], s[1]); p[1] = pack2(s[2], s[3]);
    p[2] = pack2(s[4], s[5]); p[3] = pack2(s[6], s[7]);
    __builtin_nontemporal_store(p,
        (uint4v*)&Xb2[(size_t)(v >> 4) * 2048 + kg * 128 + (v & 15) * 8]);
}

// ---------------- layer-2 SpMM (f32 H, 16-feature chunks) ----------------
__global__ __launch_bounds__(256) void k_spmm_f32(
        const float* __restrict__ Hc, const unsigned* __restrict__ ew,
        const float* __restrict__ invden, const float* __restrict__ bias,
        const int* __restrict__ off, float* __restrict__ out, int n) {
    const int chunk = blockIdx.x & 3;             // NCH = 64/16 = 4
    const int v = (blockIdx.x >> 2) * 64 + (threadIdx.x >> 2);
    if (v >= n) return;
    const int q = threadIdx.x & 3;                // feature quad 0..3
    const int start = off[v], end = off[v + 1];
    const float* __restrict__ Hch = Hc + (size_t)chunk * (size_t)n * 16 + q * 4;

    float4 a0 = make_float4(0.f, 0.f, 0.f, 0.f);
    float4 a1 = make_float4(0.f, 0.f, 0.f, 0.f);
    float4 a2 = make_float4(0.f, 0.f, 0.f, 0.f);
    float4 a3 = make_float4(0.f, 0.f, 0.f, 0.f);

    #define GAT(E, A)                                                  \
        {                                                              \
            float w_ = __uint_as_float((E) << 16);                     \
            float4 h_ = *(const float4*)&Hch[(size_t)((E) >> 16) * 16];\
            A.x += w_ * h_.x; A.y += w_ * h_.y;                        \
            A.z += w_ * h_.z; A.w += w_ * h_.w;                        \
        }
    #define GAT4(Q) GAT((Q).x, a0) GAT((Q).y, a1) GAT((Q).z, a2) GAT((Q).w, a3)

    int j = start;
    for (; j + 4 < end; j += 8) {
        uint4 eA = *(const uint4*)&ew[j];
        uint4 eB = *(const uint4*)&ew[j + 4];
        GAT4(eA)
        GAT4(eB)
    }
    if (j < end) {
        uint4 eA = *(const uint4*)&ew[j];
        GAT4(eA)
    }
    #undef GAT4
    #undef GAT

    const float inv = invden[v];
    const float4 b = *(const float4*)&bias[chunk * 16 + q * 4];
    float4v o;
    o[0] = (a0.x + a1.x + a2.x + a3.x) * inv + b.x;
    o[1] = (a0.y + a1.y + a2.y + a3.y) * inv + b.y;
    o[2] = (a0.z + a1.z + a2.z + a3.z) * inv + b.z;
    o[3] = (a0.w + a1.w + a2.w + a3.w) * inv + b.w;
    __builtin_nontemporal_store(o, (float4v*)&out[(size_t)v * OUT_CH + chunk * 16 + q * 4]);
}

// ---------------- launch ----------------

extern "C" void kernel_launch(void* const* d_in, const int* in_sizes, int n_in,
                              void* d_out, int out_size, void* d_ws, size_t ws_size,
                              hipStream_t stream) {
    const float* x     = (const float*)d_in[0];
    const int*   ei    = (const int*)d_in[1];
    const float* W1    = (const float*)d_in[2];
    const float* as1   = (const float*)d_in[3];
    const float* ad1   = (const float*)d_in[4];
    const float* b1    = (const float*)d_in[5];
    const float* W2    = (const float*)d_in[6];
    const float* as2   = (const float*)d_in[7];
    const float* ad2   = (const float*)d_in[8];
    const float* b2    = (const float*)d_in[9];
    float* out = (float*)d_out;

    const int Nn = N_NODES, E = N_EDGES, ET = N_TOT_EDGES;

    // workspace carve-up (256B aligned)
    char* ws = (char*)d_ws;
    size_t o = 0;
    auto carve = [&](size_t bytes) { char* p = ws + o; o = (o + bytes + 255) & ~(size_t)255; return p; };
    int*            off  = (int*)carve((Nn + 1) * sizeof(int));
    int*            cnt  = (int*)carve(Nn * sizeof(int));
    int*            bsum = (int*)carve(256 * sizeof(int));
    unsigned short* rank = (unsigned short*)carve((size_t)E * sizeof(unsigned short));
    int*            csr  = (int*)carve((size_t)ET_PAD * sizeof(int));
    unsigned*       ew   = (unsigned*)carve((size_t)ET_PAD * sizeof(unsigned));
    unsigned short* h1b  = (unsigned short*)carve((size_t)Nn * HID * sizeof(unsigned short));
    float*          h2   = (float*)carve((size_t)Nn * OUT_CH * sizeof(float));
    unsigned short* Xb1  = (unsigned short*)carve((size_t)MPAD * 128 * sizeof(unsigned short));
    unsigned short* Xb2  = (unsigned short*)carve((size_t)MPAD * 128 * sizeof(unsigned short));
    unsigned short* Wl1  = (unsigned short*)carve(16 * 128 * 8 * sizeof(unsigned short));
    unsigned short* Wl2  = (unsigned short*)carve(16 * 64 * 8 * sizeof(unsigned short));
    float*          als  = (float*)carve(Nn * sizeof(float));
    float*          ald  = (float*)carve(Nn * sizeof(float));
    float*          invd = (float*)carve(Nn * sizeof(float));

    const int nbN   = (Nn + 255) / 256;
    const int nbE   = (E + 255) / 256;
    const int nbET  = (ET + 255) / 256;

    // CSR build: count captures ranks; fill is atomic-free
    k_init_cnt<<<nbN, 256, 0, stream>>>(cnt, Nn);
    k_count<<<nbE, 256, 0, stream>>>(ei + E, cnt, rank, E);
    k_scan1<<<nbN, 256, 0, stream>>>(cnt, off, bsum, Nn);
    k_scan2<<<1, 256, 0, stream>>>(bsum, nbN);
    k_scan3<<<nbN, 256, 0, stream>>>(off, bsum, Nn);
    k_fill2<<<nbET, 256, 0, stream>>>(ei, off, rank, csr, E, Nn);
    hipMemsetAsync(ew, 0, (size_t)ET_PAD * sizeof(unsigned), stream);  // pads -> (src=0, w=0)

    // bf16 conversions for MFMA
    k_cvtX<<<MPAD / 16, 256, 0, stream>>>(x, Xb1, Nn);
    k_cvtW<128><<<(16 * 128) / 256, 256, 0, stream>>>(W1, Wl1);
    k_cvtW<64><<<(16 * 64) / 256, 256, 0, stream>>>(W2, Wl2);

    const int nbEW   = (Nn + 15) / 16;
    const int nbN64  = (Nn + 63) / 64;
    const int nbGEMM = MPAD / 64;   // 782

    // layer 1
    gemm_mfma<HID, true><<<nbGEMM, 256, 0, stream>>>(
        Xb1, Wl1, as1, ad1, h1b, als, ald, Nn);
    k_edgew<<<nbEW, 256, 0, stream>>>(als, ald, off, cnt, csr, ew, invd, Nn);
    k_spmm_bf16<<<nbN64 * 4, 256, 0, stream>>>(h1b, ew, invd, b1, off, Xb2, Nn);

    // layer 2
    gemm_mfma<OUT_CH, false><<<nbGEMM, 256, 0, stream>>>(
        Xb2, Wl2, as2, ad2, h2, als, ald, Nn);
    k_edgew<<<nbEW, 256, 0, stream>>>(als, ald, off, cnt, csr, ew, invd, Nn);
    k_spmm_f32<<<nbN64 * 4, 256, 0, stream>>>(h2, ew, invd, b2, off, out, Nn);
}